// Round 6
// baseline (38.726 us; speedup 1.0000x reference)
//
#include <hip/hip_runtime.h>
#include <cstdint>

#define OUTF 12288
#define INF  4096
#define NG   32
#define BATCH 8

// ---- main path geometry (K-split) ----
#define BLOCK 512
#define WAVES 8
#define RPW 2                 // rows per wave
#define RPB (WAVES*RPW)       // 16 rows per block
#define NBLK ((OUTF/RPB)*2)   // 768 row-blocks x 2 k-halves = 1536

// ws layout: [0,64K) x16 fp16 ; [64K, 64K+768K) partials [2][8][12288] f32
#define WS_X16_BYTES   65536
#define WS_PART_FLOATS 98304
#define WS_NEEDED      (WS_X16_BYTES + 2*WS_PART_FLOATS*4)

typedef _Float16 half2_t __attribute__((ext_vector_type(2)));

__device__ __forceinline__ float dot2(half2_t a, half2_t b, float c) {
#if __has_builtin(__builtin_amdgcn_fdot2)
    return __builtin_amdgcn_fdot2(a, b, c, false);
#else
    return c + (float)(a.x) * (float)(b.x) + (float)(a.y) * (float)(b.y);
#endif
}
__device__ __forceinline__ half2_t pk16(float a, float b) {
    return __builtin_bit_cast(half2_t, __builtin_amdgcn_cvt_pkrtz(a, b));
}

// ---- kernel A: x fp32 -> fp16 (packed pairs) into ws ----
__global__ __launch_bounds__(256) void qlin_cvt(
    const float* __restrict__ x, uint32_t* __restrict__ x16)
{
    const int i = blockIdx.x * 256 + threadIdx.x;   // 16384 pairs
    const float2 v = reinterpret_cast<const float2*>(x)[i];
    x16[i] = __builtin_bit_cast(uint32_t, pk16(v.x, v.y));
}

// ---- kernel B: main GEMV over one k-half, partials to ws ----
__global__ __launch_bounds__(BLOCK, 8) void qlin_main(
    const int*      __restrict__ qc,      // [12288][2048] int32 (one byte/elem)
    const float*    __restrict__ scales,  // [12288][32]
    const float*    __restrict__ zeros,   // [12288][32]
    const uint16_t* __restrict__ x16,     // [8][4096] fp16
    float*          __restrict__ part)    // [2][8][12288] f32
{
    __shared__ uint4 xs[2048];            // 32 KiB: [b][slot<256] of 8 fp16

    const int tid  = threadIdx.x;
    const int wave = tid >> 6;
    const int lane = tid & 63;
    const int rb   = blockIdx.x >> 1;
    const int kh   = blockIdx.x & 1;
    const int row0 = rb * RPB + wave * RPW;

    // stage this k-half's x (fp16) : wave w copies batch row w (4 KB)
    #pragma unroll
    for (int c = 0; c < 4; ++c) {
        const int s = c * 64 + lane;
        xs[wave * 256 + s] = *reinterpret_cast<const uint4*>(
            x16 + wave * INF + kh * 2048 + s * 8);
    }

    // per-row bases: at step h (0..3), lane covers k-half-local k' in
    // [h*512 + lane*8, +8) -> group g = kh*16 + h*4 + (lane>>4)
    const int* qq[RPW];
    int soff[RPW];
    #pragma unroll
    for (int r = 0; r < RPW; ++r) {
        const int o = row0 + r;
        qq[r]   = qc + o * 2048 + kh * 1024 + lane * 4;
        soff[r] = o * NG + kh * 16 + (lane >> 4);
    }

    // prologue: q + sc/zp for h=0 (issued before barrier)
    uint4 tA[RPW];
    float sA[RPW], nzA[RPW];
    #pragma unroll
    for (int r = 0; r < RPW; ++r) {
        tA[r]  = *reinterpret_cast<const uint4*>(qq[r]);
        sA[r]  = scales[soff[r]];
        nzA[r] = -zeros[soff[r]] * sA[r];
    }

    float y[RPW][BATCH];
    #pragma unroll
    for (int r = 0; r < RPW; ++r)
        #pragma unroll
        for (int b = 0; b < BATCH; ++b) y[r][b] = 0.f;

    __syncthreads();

    #pragma unroll
    for (int h = 0; h < 4; ++h) {
        uint4 tN[RPW];
        float sB[RPW], nzB[RPW];
        if (h < 3) {
            #pragma unroll
            for (int r = 0; r < RPW; ++r) {
                tN[r]  = *reinterpret_cast<const uint4*>(qq[r] + (h + 1) * 256);
                sB[r]  = scales[soff[r] + (h + 1) * 4];
                nzB[r] = -zeros[soff[r] + (h + 1) * 4] * sB[r];
            }
        }

        // unpack + pre-scale (hi nibble = even k)
        half2_t wp[RPW][4];
        #pragma unroll
        for (int r = 0; r < RPW; ++r) {
            #pragma unroll
            for (int e = 0; e < 4; ++e) {
                const uint32_t ei = (e == 0) ? tA[r].x : (e == 1) ? tA[r].y
                                 : (e == 2) ? tA[r].z : tA[r].w;
                const float hi = (float)((ei >> 4) & 0xFu);
                const float lo = (float)( ei       & 0xFu);
                wp[r][e] = pk16(fmaf(hi, sA[r], nzA[r]),
                                fmaf(lo, sA[r], nzA[r]));
            }
        }

        const int slot = h * 64 + lane;       // lane-consecutive: no conflicts
        #pragma unroll
        for (int b = 0; b < BATCH; ++b) {
            const uint4 v = xs[b * 256 + slot];
            const half2_t x0 = __builtin_bit_cast(half2_t, v.x);
            const half2_t x1 = __builtin_bit_cast(half2_t, v.y);
            const half2_t x2 = __builtin_bit_cast(half2_t, v.z);
            const half2_t x3 = __builtin_bit_cast(half2_t, v.w);
            #pragma unroll
            for (int r = 0; r < RPW; ++r) {
                y[r][b] = dot2(wp[r][0], x0, y[r][b]);
                y[r][b] = dot2(wp[r][1], x1, y[r][b]);
                y[r][b] = dot2(wp[r][2], x2, y[r][b]);
                y[r][b] = dot2(wp[r][3], x3, y[r][b]);
            }
        }

        #pragma unroll
        for (int r = 0; r < RPW; ++r) {
            if (h < 3) { tA[r] = tN[r]; sA[r] = sB[r]; nzA[r] = nzB[r]; }
        }
    }

    // butterfly; lane (r*8+b) keeps value (r,b); lanes 0-15 store partials
    float keep = 0.f;
    #pragma unroll
    for (int r = 0; r < RPW; ++r) {
        #pragma unroll
        for (int b = 0; b < BATCH; ++b) {
            float v = y[r][b];
            #pragma unroll
            for (int m = 1; m < 64; m <<= 1) v += __shfl_xor(v, m, 64);
            if (lane == r * 8 + b) keep = v;
        }
    }
    if (lane < RPW * BATCH) {
        const int r = lane >> 3, b = lane & 7;
        part[kh * WS_PART_FLOATS + b * OUTF + row0 + r] = keep;
    }
}

// ---- kernel C: combine partials + bias -> out ----
__global__ __launch_bounds__(256) void qlin_combine(
    const float* __restrict__ part, const float* __restrict__ bias,
    float* __restrict__ out)
{
    const int i4 = blockIdx.x * 256 + threadIdx.x;  // 24576 float4s
    const int b  = i4 / (OUTF / 4);
    const int o4 = (i4 - b * (OUTF / 4)) * 4;
    const float4 p0 = *reinterpret_cast<const float4*>(part + b * OUTF + o4);
    const float4 p1 = *reinterpret_cast<const float4*>(part + WS_PART_FLOATS + b * OUTF + o4);
    const float4 bb = *reinterpret_cast<const float4*>(bias + o4);
    float4 o;
    o.x = p0.x + p1.x + bb.x; o.y = p0.y + p1.y + bb.y;
    o.z = p0.z + p1.z + bb.z; o.w = p0.w + p1.w + bb.w;
    *reinterpret_cast<float4*>(out + b * OUTF + o4) = o;
}

// ---- fallback: round-5 single kernel (proven) if ws too small ----
__global__ __launch_bounds__(512, 4) void qlin_fb(
    const float* __restrict__ x, const int* __restrict__ qc,
    const float* __restrict__ scales, const float* __restrict__ zeros,
    const float* __restrict__ bias, float* __restrict__ out)
{
    __shared__ uint4 xs[4096];
    const int tid = threadIdx.x, wave = tid >> 6, lane = tid & 63;
    const int row0 = blockIdx.x * 24 + wave * 3;
    #pragma unroll
    for (int i = 0; i < 8; ++i) {
        const float4 v0 = *reinterpret_cast<const float4*>(x + i * INF + tid * 8);
        const float4 v1 = *reinterpret_cast<const float4*>(x + i * INF + tid * 8 + 4);
        uint4 w;
        w.x = __builtin_bit_cast(uint32_t, pk16(v0.x, v0.y));
        w.y = __builtin_bit_cast(uint32_t, pk16(v0.z, v0.w));
        w.z = __builtin_bit_cast(uint32_t, pk16(v1.x, v1.y));
        w.w = __builtin_bit_cast(uint32_t, pk16(v1.z, v1.w));
        xs[i * 512 + tid] = w;
    }
    const int* qp[3]; const float* scb[3]; const float* zpb[3];
    #pragma unroll
    for (int r = 0; r < 3; ++r) {
        const int o = row0 + r;
        qp[r] = qc + o * 2048 + lane * 4;
        scb[r] = scales + o * NG + (lane >> 4);
        zpb[r] = zeros  + o * NG + (lane >> 4);
    }
    uint4 tA[3], tB[3]; float sA[3], nzA[3], sB[3], nzB[3];
    #pragma unroll
    for (int r = 0; r < 3; ++r) {
        tA[r] = *reinterpret_cast<const uint4*>(qp[r]);
        tB[r] = *reinterpret_cast<const uint4*>(qp[r] + 256);
        sA[r] = scb[r][0]; nzA[r] = -zpb[r][0] * sA[r];
    }
    float y[3][8];
    #pragma unroll
    for (int r = 0; r < 3; ++r)
        #pragma unroll
        for (int b = 0; b < 8; ++b) y[r][b] = 0.f;
    __syncthreads();
    #pragma unroll
    for (int h = 0; h < 8; ++h) {
        uint4 tN[3];
        if (h < 6)
            #pragma unroll
            for (int r = 0; r < 3; ++r)
                tN[r] = *reinterpret_cast<const uint4*>(qp[r] + (h + 2) * 256);
        if (h < 7)
            #pragma unroll
            for (int r = 0; r < 3; ++r) {
                sB[r] = scb[r][(h + 1) * 4]; nzB[r] = -zpb[r][(h + 1) * 4] * sB[r];
            }
        half2_t wp[3][4];
        #pragma unroll
        for (int r = 0; r < 3; ++r)
            #pragma unroll
            for (int e = 0; e < 4; ++e) {
                const uint32_t ei = (e == 0) ? tA[r].x : (e == 1) ? tA[r].y
                                 : (e == 2) ? tA[r].z : tA[r].w;
                wp[r][e] = pk16(fmaf((float)((ei >> 4) & 0xFu), sA[r], nzA[r]),
                                fmaf((float)( ei       & 0xFu), sA[r], nzA[r]));
            }
        const int slot = h * 64 + lane;
        #pragma unroll
        for (int b = 0; b < 8; ++b) {
            const uint4 v = xs[b * 512 + slot];
            const half2_t x0 = __builtin_bit_cast(half2_t, v.x);
            const half2_t x1 = __builtin_bit_cast(half2_t, v.y);
            const half2_t x2 = __builtin_bit_cast(half2_t, v.z);
            const half2_t x3 = __builtin_bit_cast(half2_t, v.w);
            #pragma unroll
            for (int r = 0; r < 3; ++r) {
                y[r][b] = dot2(wp[r][0], x0, y[r][b]);
                y[r][b] = dot2(wp[r][1], x1, y[r][b]);
                y[r][b] = dot2(wp[r][2], x2, y[r][b]);
                y[r][b] = dot2(wp[r][3], x3, y[r][b]);
            }
        }
        #pragma unroll
        for (int r = 0; r < 3; ++r) {
            tA[r] = tB[r];
            if (h < 6) tB[r] = tN[r];
            if (h < 7) { sA[r] = sB[r]; nzA[r] = nzB[r]; }
        }
    }
    float keep = 0.f;
    #pragma unroll
    for (int r = 0; r < 3; ++r)
        #pragma unroll
        for (int b = 0; b < 8; ++b) {
            float v = y[r][b];
            #pragma unroll
            for (int m = 1; m < 64; m <<= 1) v += __shfl_xor(v, m, 64);
            if (lane == r * 8 + b) keep = v;
        }
    if (lane < 24) {
        const int r = lane >> 3, b = lane & 7;
        const int o = row0 + r;
        out[b * OUTF + o] = keep + bias[o];
    }
}

extern "C" void kernel_launch(void* const* d_in, const int* in_sizes, int n_in,
                              void* d_out, int out_size, void* d_ws, size_t ws_size,
                              hipStream_t stream) {
    const float* x      = (const float*)d_in[0];
    const int*   qcodes = (const int*)  d_in[1];
    const float* scales = (const float*)d_in[2];
    const float* zeros  = (const float*)d_in[3];
    const float* bias   = (const float*)d_in[4];
    float* out = (float*)d_out;

    if (ws_size >= (size_t)WS_NEEDED) {
        uint32_t* x16u = (uint32_t*)d_ws;
        float*    part = (float*)((char*)d_ws + WS_X16_BYTES);
        qlin_cvt<<<64, 256, 0, stream>>>(x, x16u);
        qlin_main<<<NBLK, BLOCK, 0, stream>>>(qcodes, scales, zeros,
                                              (const uint16_t*)x16u, part);
        qlin_combine<<<96, 256, 0, stream>>>(part, bias, out);
    } else {
        qlin_fb<<<512, 512, 0, stream>>>(x, qcodes, scales, zeros, bias, out);
    }
}

// Round 7
// 31.735 us; speedup vs baseline: 1.2203x; 1.2203x over previous
//
#include <hip/hip_runtime.h>
#include <cstdint>

#define OUTF 12288
#define INF  4096
#define NG   32
#define BATCH 8

#define BLOCK 512
#define WAVES 8
#define RPW 3                  // rows per wave
#define RPB (WAVES*RPW)        // 24 rows per block
#define NBLK (OUTF/RPB)        // 512 blocks -> 2 balanced rounds of 256 CUs

typedef _Float16 half2_t __attribute__((ext_vector_type(2)));

__device__ __forceinline__ float dot2(half2_t a, half2_t b, float c) {
#if __has_builtin(__builtin_amdgcn_fdot2)
    return __builtin_amdgcn_fdot2(a, b, c, false);
#else
    return c + (float)(a.x) * (float)(b.x) + (float)(a.y) * (float)(b.y);
#endif
}
__device__ __forceinline__ half2_t pk16(float a, float b) {
    return __builtin_bit_cast(half2_t, __builtin_amdgcn_cvt_pkrtz(a, b));
}

// async global->LDS, 16B per lane; LDS dest = wave-uniform base + lane*16
__device__ __forceinline__ void gload_lds16(const int* g, void* l) {
    __builtin_amdgcn_global_load_lds(
        (const __attribute__((address_space(1))) uint32_t*)g,
        (__attribute__((address_space(3))) uint32_t*)l, 16, 0, 0);
}

__global__ __launch_bounds__(BLOCK, 2) void qlin_kernel(
    const float* __restrict__ x,       // [8][4096] fp32
    const int*   __restrict__ qc,      // [12288][2048] int32, one packed byte/elem
    const float* __restrict__ scales,  // [12288][32]
    const float* __restrict__ zeros,   // [12288][32]
    const float* __restrict__ bias,    // [12288]
    float* __restrict__ out)           // [8][12288]
{
    __shared__ uint4 xs[4096];                    // 64 KiB x as fp16, linear
    __shared__ uint4 qring[WAVES * 2 * RPW * 64]; // 48 KiB: [wave][slot][row][64]
    __shared__ float scz[RPB * NG * 2];           // 6 KiB: [row][g][{sc,zp}]

    const int tid   = threadIdx.x;
    const int wave  = tid >> 6;
    const int lane  = tid & 63;
    const int rbase = blockIdx.x * RPB;
    const int row0  = rbase + wave * RPW;

    // q row base pointers (int32 elements); stage h covers ints [h*256+lane*4,+4)
    const int* qq[RPW];
    #pragma unroll
    for (int r = 0; r < RPW; ++r)
        qq[r] = qc + (row0 + r) * 2048 + lane * 4;

    // ---- prologue: issue q stages h=0,1 first (no dependencies) ----
    #pragma unroll
    for (int r = 0; r < RPW; ++r)
        gload_lds16(qq[r],       &qring[((wave * 2 + 0) * RPW + r) * 64]);
    #pragma unroll
    for (int r = 0; r < RPW; ++r)
        gload_lds16(qq[r] + 256, &qring[((wave * 2 + 1) * RPW + r) * 64]);

    // ---- stage ALL of x as fp16 (linear; lane-consecutive reads later) ----
    #pragma unroll
    for (int i = 0; i < 8; ++i) {
        const float4 v0 = *reinterpret_cast<const float4*>(x + i * INF + tid * 8);
        const float4 v1 = *reinterpret_cast<const float4*>(x + i * INF + tid * 8 + 4);
        uint4 w;
        w.x = __builtin_bit_cast(uint32_t, pk16(v0.x, v0.y));
        w.y = __builtin_bit_cast(uint32_t, pk16(v0.z, v0.w));
        w.z = __builtin_bit_cast(uint32_t, pk16(v1.x, v1.y));
        w.w = __builtin_bit_cast(uint32_t, pk16(v1.z, v1.w));
        xs[i * 512 + tid] = w;
    }

    // ---- stage sc/zp table: [r_local][g] pairs ----
    for (int i = tid; i < RPB * NG; i += BLOCK) {
        const int r = i >> 5, g = i & 31;
        scz[i * 2]     = scales[(rbase + r) * NG + g];
        scz[i * 2 + 1] = zeros [(rbase + r) * NG + g];
    }

    float y[RPW][BATCH];
    #pragma unroll
    for (int r = 0; r < RPW; ++r)
        #pragma unroll
        for (int b = 0; b < BATCH; ++b) y[r][b] = 0.f;

    __syncthreads();   // the only barrier (also drains prologue stages -> ready)

    #pragma unroll
    for (int h = 0; h < 8; ++h) {
        // stage h resident once <=3 younger loads outstanding
        if (h < 7) asm volatile("s_waitcnt vmcnt(3)" ::: "memory");
        else       asm volatile("s_waitcnt vmcnt(0)" ::: "memory");
        __builtin_amdgcn_sched_barrier(0);

        // read this h's q chunks from ring slot h&1 (contiguous b128, no conflicts)
        uint4 t[RPW];
        #pragma unroll
        for (int r = 0; r < RPW; ++r)
            t[r] = qring[((wave * 2 + (h & 1)) * RPW + r) * 64 + lane];

        // refill same slot for h+2 ((h+2)&1 == h&1); write lands >=200cy out
        if (h < 6) {
            #pragma unroll
            for (int r = 0; r < RPW; ++r)
                gload_lds16(qq[r] + (h + 2) * 256,
                            &qring[((wave * 2 + (h & 1)) * RPW + r) * 64]);
        }

        // per-(h,r) scale/zero from LDS table: g = h*4 + (lane>>4)
        float sc_[RPW], nz_[RPW];
        #pragma unroll
        for (int r = 0; r < RPW; ++r) {
            const int idx = ((wave * RPW + r) * NG + (h * 4 + (lane >> 4))) * 2;
            sc_[r] = scz[idx];
            nz_[r] = -scz[idx + 1] * sc_[r];
        }

        // unpack + pre-scale (hi nibble = even k) -- round-5-proven mapping
        half2_t wp[RPW][4];
        #pragma unroll
        for (int r = 0; r < RPW; ++r) {
            #pragma unroll
            for (int e = 0; e < 4; ++e) {
                const uint32_t ei = (e == 0) ? t[r].x : (e == 1) ? t[r].y
                                 : (e == 2) ? t[r].z : t[r].w;
                const float hi = (float)((ei >> 4) & 0xFu);
                const float lo = (float)( ei       & 0xFu);
                wp[r][e] = pk16(fmaf(hi, sc_[r], nz_[r]),
                                fmaf(lo, sc_[r], nz_[r]));
            }
        }

        const int slot = h * 64 + lane;   // lane-consecutive: conflict-free
        #pragma unroll
        for (int b = 0; b < BATCH; ++b) {
            const uint4 v = xs[b * 512 + slot];
            const half2_t x0 = __builtin_bit_cast(half2_t, v.x);
            const half2_t x1 = __builtin_bit_cast(half2_t, v.y);
            const half2_t x2 = __builtin_bit_cast(half2_t, v.z);
            const half2_t x3 = __builtin_bit_cast(half2_t, v.w);
            #pragma unroll
            for (int r = 0; r < RPW; ++r) {
                y[r][b] = dot2(wp[r][0], x0, y[r][b]);
                y[r][b] = dot2(wp[r][1], x1, y[r][b]);
                y[r][b] = dot2(wp[r][2], x2, y[r][b]);
                y[r][b] = dot2(wp[r][3], x3, y[r][b]);
            }
        }
    }

    // 64-lane butterfly; lane (r*8+b) keeps value (r,b)
    float keep = 0.f;
    #pragma unroll
    for (int r = 0; r < RPW; ++r) {
        #pragma unroll
        for (int b = 0; b < BATCH; ++b) {
            float v = y[r][b];
            #pragma unroll
            for (int m = 1; m < 64; m <<= 1) v += __shfl_xor(v, m, 64);
            if (lane == r * 8 + b) keep = v;
        }
    }
    if (lane < RPW * BATCH) {
        const int r = lane >> 3, b = lane & 7;
        const int o = row0 + r;
        out[b * OUTF + o] = keep + bias[o];
    }
}

extern "C" void kernel_launch(void* const* d_in, const int* in_sizes, int n_in,
                              void* d_out, int out_size, void* d_ws, size_t ws_size,
                              hipStream_t stream) {
    const float* x      = (const float*)d_in[0];
    const int*   qcodes = (const int*)  d_in[1];
    const float* scales = (const float*)d_in[2];
    const float* zeros  = (const float*)d_in[3];
    const float* bias   = (const float*)d_in[4];
    float* out = (float*)d_out;

    qlin_kernel<<<NBLK, BLOCK, 0, stream>>>(x, qcodes, scales, zeros, bias, out);
}